// Round 4
// baseline (1811.873 us; speedup 1.0000x reference)
//
#include <hip/hip_runtime.h>
#include <stdint.h>

// ---------------------------------------------------------------------------
// Net_52948356825721: 4x edge-conv GNN.
// h1 = relu( P_row[row] + P_col[col] + (ef @ W_e) + b1 ),
//   P = nodefeat @ [W_r | W_c]  ([N,128] f32 dense GEMM).
// o = h1 @ w2 + b2 ; scatter-mean(o) on row ; edge_x = relu(o) (convs 1-3).
//
// R1-R3 NaN'd regardless of scratch strategy -> theory: I/O dtype is FLOAT32
// (reference uses jnp.float32 explicitly), not bf16. Reading f32 as u16 makes
// NaN exponents from mantissa low halves. This round: device-side dtype
// detection (g_mode) + dual bf16/f32 bodies. Weight sub-matrix offsets are in
// ELEMENTS, applied on typed pointers inside the kernels (traits NGOff/ECOff)
// since element size is mode-dependent. edge_index int32/int64 detected too.
// Scratch in __device__ globals (~82 MB .bss); d_ws unused.
// ---------------------------------------------------------------------------

#define N_NODES 10000
#define N_EDGES 128000
#define E_HALF  64000

typedef unsigned short u16;
constexpr int PAD = 18;

__device__ __align__(256) float g_acc[N_NODES * 64];
__device__ __align__(256) float g_deg[N_NODES];
__device__ __align__(256) float g_P[N_NODES * 128];
__device__ __align__(256) float g_x1[N_NODES * 64];
__device__ __align__(256) float g_x2[N_NODES * 64];
__device__ __align__(256) float g_x3[N_NODES * 64];
__device__ __align__(256) unsigned char g_exA[(size_t)N_EDGES * 64 * 4];
__device__ __align__(256) unsigned char g_exB[(size_t)N_EDGES * 64 * 4];
__device__ __align__(256) int g_row[N_EDGES];
__device__ __align__(256) int g_col[N_EDGES];
__device__ int g_mode;   // 0 = bf16 I/O, 1 = f32 I/O
__device__ int g_is64;   // edge_index is int64

__device__ __forceinline__ float b2f(u16 u) {
    return __uint_as_float(((unsigned int)u) << 16);
}
__device__ __forceinline__ u16 f2b(float f) {
    unsigned int u = __float_as_uint(f);
    u += 0x7FFFu + ((u >> 16) & 1u);   // RNE
    return (u16)(u >> 16);
}
__device__ __forceinline__ float ldf(const u16* p)   { return b2f(*p); }
__device__ __forceinline__ float ldf(const float* p) { return *p; }
__device__ __forceinline__ void  stf(u16* p, float v)   { *p = f2b(v); }
__device__ __forceinline__ void  stf(float* p, float v) { *p = v; }

// weight sub-matrix ELEMENT offsets (dtype-size independent)
template<int K1, int K2> struct NGOff;
template<> struct NGOff<256, 4> { static constexpr size_t hi = (size_t)260 * 64; };
template<> struct NGOff<64, 0>  { static constexpr size_t hi = (size_t)64 * 64; };
template<> struct NGOff<64, 64> { static constexpr size_t hi = (size_t)128 * 64; };
template<int DA, int DB> struct ECOff;
template<> struct ECOff<640, 4>  { static constexpr size_t we = (size_t)520 * 64; };
template<> struct ECOff<640, 64> { static constexpr size_t we = (size_t)128 * 64; };
template<> struct ECOff<64, 64>  { static constexpr size_t we = (size_t)256 * 64; };

// stage one row (D elems) into k-major LDS tile: sm[(koff+k)*PAD + e]
template<int D>
__device__ __forceinline__ void stage_row(const u16* src, float* sm, int koff, int e, int t) {
    static_assert(D % 4 == 0, "D%4");
    for (int k = t * 4; k < D; k += 1024) {
        ushort4 v = *(const ushort4*)(src + k);
        sm[(koff + k + 0) * PAD + e] = b2f(v.x);
        sm[(koff + k + 1) * PAD + e] = b2f(v.y);
        sm[(koff + k + 2) * PAD + e] = b2f(v.z);
        sm[(koff + k + 3) * PAD + e] = b2f(v.w);
    }
}
template<int D>
__device__ __forceinline__ void stage_row(const float* src, float* sm, int koff, int e, int t) {
    static_assert(D % 4 == 0, "D%4");
    for (int k = t * 4; k < D; k += 1024) {
        float4 v = *(const float4*)(src + k);
        sm[(koff + k + 0) * PAD + e] = v.x;
        sm[(koff + k + 1) * PAD + e] = v.y;
        sm[(koff + k + 2) * PAD + e] = v.z;
        sm[(koff + k + 3) * PAD + e] = v.w;
    }
}

// --- dtype + index-width detection (1 block, 64 threads) --------------------
__global__ void detect_kernel(const void* x_org_v, const int* __restrict__ eidx) {
    const u16* w = (const u16*)x_org_v;
    const int t = threadIdx.x;
    int ok = 0;                          // bf16 plausibility of first 128 u16
    for (int i = t; i < 128; i += 64) {
        u16 v = w[i];
        int ex = (v >> 7) & 0xFF;
        ok += ((ex >= 0x68 && ex <= 0x88) || ((v & 0x7FFFu) == 0)) ? 1 : 0;
    }
    #pragma unroll
    for (int off = 32; off >= 1; off >>= 1) ok += __shfl_xor(ok, off);
    bool allz = true;                    // int64: high words all zero
    for (int i = t; i < 2048; i += 64) allz = allz && (eidx[2 * i + 1] == 0);
    unsigned long long m = __ballot(allz);
    if (t == 0) {
        g_mode = (ok >= 110) ? 0 : 1;    // bf16 ~128 pass; f32 ~72 pass
        g_is64 = (m == ~0ull) ? 1 : 0;
    }
}

__global__ void cvt_idx(const int* __restrict__ eidx) {
    const int e = blockIdx.x * 256 + threadIdx.x;   // exact: 500*256
    if (g_is64) {
        g_row[e] = eidx[2 * e];
        g_col[e] = eidx[2 * (e + N_EDGES)];
    } else {
        g_row[e] = eidx[e];
        g_col[e] = eidx[e + N_EDGES];
    }
}

__global__ void zero_all() {
    const int i = blockIdx.x * 256 + threadIdx.x;   // 2500 blocks -> 640000
    g_acc[i] = 0.f;
    if (i < N_NODES) g_deg[i] = 0.f;
}

__global__ void deg_kernel() {
    const int e = blockIdx.x * 256 + threadIdx.x;
    if (e < N_EDGES) atomicAdd(&g_deg[g_row[e]], 1.0f);
}

// --- P[n,0:64] = [A1|A2] @ W[0:K] ; P[n,64:128] = [A1|A2] @ W[hi:hi+K] ------
template<int K1, typename TA1, int K2, typename TA2, typename TW>
__device__ void node_gemm_body(float* sm, const TA1* A1, const TA2* A2,
                               const TW* Wbase, float* P) {
    constexpr int K = K1 + K2;
    const TW* Blo = Wbase;
    const TW* Bhi = Wbase + NGOff<K1, K2>::hi;
    const int t = threadIdx.x;
    const int c = t & 127;
    const int g = t >> 7;
    const int r0 = blockIdx.x * 16;
    for (int e = 0; e < 16; ++e) {
        stage_row<K1>(A1 + (size_t)(r0 + e) * K1, sm, 0, e, t);
        if constexpr (K2 > 0)
            stage_row<K2>(A2 + (size_t)(r0 + e) * K2, sm, K1, e, t);
    }
    __syncthreads();
    float acc[16];
    #pragma unroll
    for (int e = 0; e < 16; ++e) acc[e] = 0.f;
    const TW* Bp = (c < 64) ? (Blo + c) : (Bhi + (c - 64));
    const int kb = g * (K / 2), ke = kb + K / 2;
    for (int k = kb; k < ke; ++k) {
        float w = ldf(Bp + (size_t)k * 64);
        #pragma unroll
        for (int e = 0; e < 16; ++e) acc[e] += sm[k * PAD + e] * w;
    }
    __syncthreads();                               // reuse sm: red[2][16][128]
    #pragma unroll
    for (int e = 0; e < 16; ++e) sm[(g * 16 + e) * 128 + c] = acc[e];
    __syncthreads();
    #pragma unroll
    for (int j = 0; j < 8; ++j) {
        int e = g * 8 + j;
        P[(size_t)(r0 + e) * 128 + c] = sm[e * 128 + c] + sm[(16 + e) * 128 + c];
    }
}

// conv1: A in input dtype
template<int K1, int K2>
__global__ void __launch_bounds__(256) node_gemm_in(
        const void* A1, const void* A2, const void* W, float* __restrict__ P) {
    extern __shared__ float sm[];
    if (g_mode == 0)
        node_gemm_body<K1, u16, K2, u16, u16>(sm, (const u16*)A1, (const u16*)A2,
                                              (const u16*)W, P);
    else
        node_gemm_body<K1, float, K2, float, float>(sm, (const float*)A1,
                                              (const float*)A2, (const float*)W, P);
}

// conv2-4: A is f32 workspace
template<int K1, int K2>
__global__ void __launch_bounds__(256) node_gemm_ws(
        const float* A1, const float* A2, const void* W, float* __restrict__ P) {
    extern __shared__ float sm[];
    if (g_mode == 0)
        node_gemm_body<K1, float, K2, float, u16>(sm, A1, A2, (const u16*)W, P);
    else
        node_gemm_body<K1, float, K2, float, float>(sm, A1, A2, (const float*)W, P);
}

// --- edge conv: Q=ef@We ; h=relu(Q+P_r[row]+P_c[col]+b1) ; o=h@w2+b2 --------
template<int DA, typename TA, int DB, typename TB, typename TW, typename TO, bool RELU_OUT>
__device__ void edge_conv_body(float* sm, const TA* efa, const TB* efb,
        const TW* w1base, const TW* b1, const TW* w2, const TW* b2, TO* eout) {
    constexpr int KE = DA + DB;
    const TW* We = w1base + ECOff<DA, DB>::we;
    __shared__ int srow[16], scol[16];
    const int t = threadIdx.x;
    const int c = t & 63;
    const int g = t >> 6;
    const int e0 = blockIdx.x * 16;
    if (t < 16) { srow[t] = g_row[e0 + t]; scol[t] = g_col[e0 + t]; }
    for (int e = 0; e < 16; ++e) {
        stage_row<DA>(efa + (size_t)(e0 + e) * DA, sm, 0, e, t);
        stage_row<DB>(efb + (size_t)(e0 + e) * DB, sm, DA, e, t);
    }
    __syncthreads();
    float acc[16];
    #pragma unroll
    for (int e = 0; e < 16; ++e) acc[e] = 0.f;
    {
        const int kb = g * (KE / 4), kend = kb + KE / 4;
        const TW* Wp = We + c;
        for (int k = kb; k < kend; ++k) {
            float w = ldf(Wp + (size_t)k * 64);
            #pragma unroll
            for (int e = 0; e < 16; ++e) acc[e] += sm[k * PAD + e] * w;
        }
    }
    __syncthreads();                      // reuse sm: red[4][16][64] + h[16][64]
    #pragma unroll
    for (int e = 0; e < 16; ++e) sm[(g * 16 + e) * 64 + c] = acc[e];
    __syncthreads();
    {
        const float bias = ldf(b1 + c);
        #pragma unroll
        for (int j = 0; j < 4; ++j) {
            const int e = g * 4 + j;
            float v = bias
                    + g_P[(size_t)srow[e] * 128 + c]
                    + g_P[(size_t)scol[e] * 128 + 64 + c]
                    + sm[e * 64 + c] + sm[(16 + e) * 64 + c]
                    + sm[(32 + e) * 64 + c] + sm[(48 + e) * 64 + c];
            sm[4096 + e * 64 + c] = fmaxf(v, 0.f);   // h (layer-1 relu)
        }
    }
    __syncthreads();
    {
        const float bb = ldf(b2 + c);
        float o0 = bb, o1 = bb, o2 = bb, o3 = bb;
        const int eb = g * 4;
        const TW* Wp2 = w2 + c;
        for (int cc = 0; cc < 64; ++cc) {
            float w = ldf(Wp2 + (size_t)cc * 64);
            o0 += sm[4096 + (eb + 0) * 64 + cc] * w;
            o1 += sm[4096 + (eb + 1) * 64 + cc] * w;
            o2 += sm[4096 + (eb + 2) * 64 + cc] * w;
            o3 += sm[4096 + (eb + 3) * 64 + cc] * w;
        }
        float ov[4] = {o0, o1, o2, o3};
        #pragma unroll
        for (int j = 0; j < 4; ++j) {
            const int e = eb + j;
            atomicAdd(&g_acc[(size_t)srow[e] * 64 + c], ov[j]);  // pre-relu sum
            float v = RELU_OUT ? fmaxf(ov[j], 0.f) : ov[j];
            stf(eout + (size_t)(e0 + e) * 64 + c, v);
        }
    }
}

// efa/efb/eout are all in mode dtype (raw inputs and edge scratch align)
template<int DA, int DB, bool RELU_OUT>
__global__ void __launch_bounds__(256) edge_conv(
        const void* efa, const void* efb,
        const void* w1base, const void* b1, const void* w2, const void* b2,
        void* eout) {
    extern __shared__ float sm[];
    if (g_mode == 0)
        edge_conv_body<DA, u16, DB, u16, u16, u16, RELU_OUT>(sm,
            (const u16*)efa, (const u16*)efb, (const u16*)w1base, (const u16*)b1,
            (const u16*)w2, (const u16*)b2, (u16*)eout);
    else
        edge_conv_body<DA, float, DB, float, float, float, RELU_OUT>(sm,
            (const float*)efa, (const float*)efb, (const float*)w1base,
            (const float*)b1, (const float*)w2, (const float*)b2, (float*)eout);
}

// --- x_i = (acc/max(deg,1)) [relu?] -> f32 [N,64]; re-zeroes acc ------------
template<bool RELU>
__global__ void finalize_k(float* __restrict__ dst) {
    const int idx = blockIdx.x * 256 + threadIdx.x;  // exact grid
    float v = g_acc[idx] / fmaxf(g_deg[idx >> 6], 1.0f);
    g_acc[idx] = 0.f;
    if (RELU) v = fmaxf(v, 0.f);
    dst[idx] = v;
}

// --- x4=relu(mean) -> lin1 [64->4] -> L2 normalize -> out -------------------
template<typename T>
__device__ void final_node_body(const T* w, const T* b, T* out) {
    const int t = threadIdx.x;
    const int lane = t & 63;
    const int n = blockIdx.x * 4 + (t >> 6);
    float inv = 1.0f / fmaxf(g_deg[n], 1.0f);
    float x4 = fmaxf(g_acc[(size_t)n * 64 + lane] * inv, 0.0f);
    float r[4];
    #pragma unroll
    for (int j = 0; j < 4; ++j) {
        float v = x4 * ldf(w + lane * 4 + j);
        #pragma unroll
        for (int off = 32; off >= 1; off >>= 1) v += __shfl_xor(v, off);
        r[j] = v + ldf(b + j);
    }
    float nrm = sqrtf(r[0]*r[0] + r[1]*r[1] + r[2]*r[2] + r[3]*r[3]);
    float dn = fmaxf(nrm, 1e-12f);
    if (lane < 4) stf(out + n * 4 + lane, r[lane] / dn);
}
__global__ void final_node(const void* w, const void* b, void* out) {
    if (g_mode == 0) final_node_body<u16>((const u16*)w, (const u16*)b, (u16*)out);
    else             final_node_body<float>((const float*)w, (const float*)b, (float*)out);
}

// --- pred_edge_res: h=ex4[:H]+ex4[H:]; relu(h@w1+b1)@w2+b2 ------------------
template<typename T>
__device__ void edge_head_body(const T* ex4, const T* w1, const T* b1,
                               const T* w2, const T* b2, T* out) {
    __shared__ float lw1[2048];
    __shared__ float lw2[32];
    const int t = threadIdx.x;
    for (int i = t; i < 2048; i += 256) lw1[i] = ldf(w1 + i);
    if (t < 32) lw2[t] = ldf(w2 + t);
    __syncthreads();
    const int e = blockIdx.x * 256 + t;           // exact: 250*256 = 64000
    float a[32];
    #pragma unroll
    for (int j = 0; j < 32; ++j) a[j] = ldf(b1 + j);
    const T* p0 = ex4 + (size_t)e * 64;
    const T* p1 = ex4 + (size_t)(e + E_HALF) * 64;
    for (int c = 0; c < 64; ++c) {
        float h = ldf(p0 + c) + ldf(p1 + c);
        #pragma unroll
        for (int j = 0; j < 32; ++j) a[j] += h * lw1[c * 32 + j];
    }
    float s = ldf(b2);
    #pragma unroll
    for (int j = 0; j < 32; ++j) s += fmaxf(a[j], 0.f) * lw2[j];
    stf(out + e, s);
}
__global__ void __launch_bounds__(256) edge_head(const void* ex4,
        const void* w1, const void* b1, const void* w2, const void* b2,
        void* out) {
    if (g_mode == 0)
        edge_head_body<u16>((const u16*)ex4, (const u16*)w1, (const u16*)b1,
                            (const u16*)w2, (const u16*)b2, (u16*)out + 40000);
    else
        edge_head_body<float>((const float*)ex4, (const float*)w1, (const float*)b1,
                              (const float*)w2, (const float*)b2, (float*)out + 40000);
}

// --- layout tripwire: fill out with ~996.5 pattern --------------------------
__global__ void sentinel_fill(unsigned int* out, int n_words) {
    int i = blockIdx.x * 256 + threadIdx.x;
    if (i < n_words) out[i] = 0x44794479u;
}

static void* sym_addr(const void* symbol) {
    void* p = nullptr;
    (void)hipGetSymbolAddress(&p, symbol);
    return p;
}

extern "C" void kernel_launch(void* const* d_in, const int* in_sizes, int n_in,
                              void* d_out, int out_size, void* d_ws, size_t ws_size,
                              hipStream_t stream) {
    (void)d_ws; (void)ws_size;
    bool ok = (n_in == 27) && (out_size == 104000)
           && (in_sizes[0] == 2560000) && (in_sizes[2] == 256000)
           && (in_sizes[3] == 81920000) && (in_sizes[5] == 74496)
           && (in_sizes[21] == 256) && (in_sizes[25] == 32);
    if (!ok) {   // wrong layout assumption -> recognizable absmax ~996
        sentinel_fill<<<204, 256, 0, stream>>>((unsigned int*)d_out, 52000);
        return;
    }
    const void* x_org     = d_in[0];
    const void* x_rot     = d_in[1];
    const int*  eidx      = (const int*)d_in[2];
    const void* edge_attr = d_in[3];
    const void* edge_rot  = d_in[4];

    float* P   = (float*)sym_addr(HIP_SYMBOL(g_P));
    float* x1  = (float*)sym_addr(HIP_SYMBOL(g_x1));
    float* x2  = (float*)sym_addr(HIP_SYMBOL(g_x2));
    float* x3  = (float*)sym_addr(HIP_SYMBOL(g_x3));
    void*  exA = sym_addr(HIP_SYMBOL(g_exA));
    void*  exB = sym_addr(HIP_SYMBOL(g_exB));

    detect_kernel<<<1, 64, 0, stream>>>(x_org, eidx);
    cvt_idx<<<500, 256, 0, stream>>>(eidx);
    zero_all<<<2500, 256, 0, stream>>>();
    deg_kernel<<<500, 256, 0, stream>>>();

    // conv1: c1_w1 rows [0,260)=W_r, [260,520)=W_c, [520,1164)=W_e
    node_gemm_in<256, 4><<<625, 256, 18720, stream>>>(x_org, x_rot, d_in[5], P);
    edge_conv<640, 4, true><<<8000, 256, 46368, stream>>>(
        edge_attr, edge_rot, d_in[5], d_in[6], d_in[7], d_in[8], exA);  // ex1
    finalize_k<false><<<2500, 256, 0, stream>>>(x1);

    // conv2: rows [0,64)=W_r, [64,128)=W_c, [128,832)=W_e on [edge_attr|ex1]
    node_gemm_ws<64, 0><<<625, 256, 16384, stream>>>(x1, (const float*)nullptr,
                                                     d_in[9], P);
    edge_conv<640, 64, true><<<8000, 256, 50688, stream>>>(
        edge_attr, exA, d_in[9], d_in[10], d_in[11], d_in[12], exB);    // ex2
    finalize_k<true><<<2500, 256, 0, stream>>>(x2);

    // conv3: rows [0,128)=W_r on [x2|x1], [128,256)=W_c, [256,384)=W_e on [ex2|ex1]
    node_gemm_ws<64, 64><<<625, 256, 16384, stream>>>(x2, x1, d_in[13], P);
    edge_conv<64, 64, true><<<8000, 256, 20480, stream>>>(
        exB, exA, d_in[13], d_in[14], d_in[15], d_in[16], exA);  // ex3 over ex1
    finalize_k<true><<<2500, 256, 0, stream>>>(x3);

    // conv4: [x3|x2] nodes, [ex3|ex2] edges
    node_gemm_ws<64, 64><<<625, 256, 16384, stream>>>(x3, x2, d_in[17], P);
    edge_conv<64, 64, false><<<8000, 256, 20480, stream>>>(
        exA, exB, d_in[17], d_in[18], d_in[19], d_in[20], exB);  // ex4 over ex2

    final_node<<<2500, 256, 0, stream>>>(d_in[21], d_in[22], d_out);
    edge_head<<<250, 256, 0, stream>>>(exB, d_in[23], d_in[24], d_in[25], d_in[26],
                                       d_out);
}